// Round 6
// baseline (9297.313 us; speedup 1.0000x reference)
//
#include <hip/hip_runtime.h>
#include <hip/hip_bf16.h>
#include <math.h>

#define T_STEPS 256
#define NB 4096

__global__ __launch_bounds__(256, 2)
void rssm_kernel(const float* __restrict__ X, const float* __restrict__ A,
                 const float* __restrict__ H0, const float* __restrict__ G,
                 const float* __restrict__ Wih, const float* __restrict__ bih,
                 const float* __restrict__ Whh, const float* __restrict__ bhh,
                 const float* __restrict__ Wenc, const float* __restrict__ benc,
                 const float* __restrict__ Wdec, const float* __restrict__ bdec,
                 float* __restrict__ out)   // d_out is FP32 (reference outputs are jnp.float32)
{
    // fp32 weight tables in LDS (values exact; converted to fp64 at use)
    __shared__ float  sWihz[96][65];   // W_ih z-part, gathered by one-hot column
    __shared__ float  sWiha[96][17];   // W_ih a-part
    __shared__ float  sWenchT[32][64]; // enc h-part transposed [k][logit]
    __shared__ float  sWenceT[10][64]; // enc e-part transposed
    __shared__ float  sWdech[10][36];  // dec h-part rows
    __shared__ float  sWdecz[10][65];  // dec z-part, gathered
    __shared__ double sH[8][34];       // per-element h broadcast slot (intra-wave only)

    const int tid = threadIdx.x;
    const int i   = tid & 31;          // component lane within element
    const int e   = tid >> 5;          // element slot in block (0..7)
    const int n   = blockIdx.x * 8 + e;

    for (int idx = tid; idx < 96*64; idx += 256){ int r = idx >> 6, c = idx & 63; sWihz[r][c] = Wih[r*80 + c]; }
    for (int idx = tid; idx < 96*16; idx += 256){ int r = idx >> 4, c = idx & 15; sWiha[r][c] = Wih[r*80 + 64 + c]; }
    for (int idx = tid; idx < 32*64; idx += 256){ int k = idx >> 6, j = idx & 63; sWenchT[k][j] = Wenc[j*42 + k]; }
    for (int idx = tid; idx < 10*64; idx += 256){ int k = idx >> 6, j = idx & 63; sWenceT[k][j] = Wenc[j*42 + 32 + k]; }
    for (int idx = tid; idx < 10*32; idx += 256){ int o = idx >> 5, k = idx & 31; sWdech[o][k] = Wdec[o*96 + k]; }
    for (int idx = tid; idx < 10*64; idx += 256){ int o = idx >> 6, c = idx & 63; sWdecz[o][c] = Wdec[o*96 + 32 + c]; }
    __syncthreads();

    // W_hh rows {i, 32+i, 64+i} in fp32 registers (exact input values)
    float whh[3][32];
    #pragma unroll
    for (int s = 0; s < 3; ++s){
        const float4* row = reinterpret_cast<const float4*>(Whh + (s*32 + i)*32);
        #pragma unroll
        for (int c = 0; c < 8; ++c){
            float4 v = row[c];
            whh[s][4*c+0]=v.x; whh[s][4*c+1]=v.y; whh[s][4*c+2]=v.z; whh[s][4*c+3]=v.w;
        }
    }

    // biases (r,z gates merge b_ih+b_hh; n gate split: b_hh[n] sits inside r*h_n)
    const double br  = (double)bih[i]      + (double)bhh[i];
    const double bz  = (double)bih[32+i]   + (double)bhh[32+i];
    const double bni = (double)bih[64+i];
    const double bnh = (double)bhh[64+i];
    const double be0 = (double)benc[2*i], be1 = (double)benc[2*i+1];
    const float  bd  = (i < 10) ? bdec[i] : 0.0f;

    // h state: fp64, replicated across the element's 32 lanes
    double h[32];
    {
        const float4* h0p = reinterpret_cast<const float4*>(H0 + (size_t)n * 32);
        #pragma unroll
        for (int c = 0; c < 8; ++c){
            float4 v = h0p[c];
            h[4*c+0]=(double)v.x; h[4*c+1]=(double)v.y; h[4*c+2]=(double)v.z; h[4*c+3]=(double)v.w;
        }
    }
    double hown = (double)H0[(size_t)n * 32 + i];

    int zsel[8];                       // winning flat column (0..63) per z-group

    const size_t HOFF = (size_t)T_STEPS * NB * 10;   // x_logits elements
    const size_t ZOFF = HOFF + (size_t)T_STEPS * NB * 32;
    const int base = tid & 32;         // element's lane base within the wave

    #pragma unroll 1
    for (int t = 0; t < T_STEPS; ++t){
        const size_t tn = (size_t)t * NB + n;

        // loads for this step (independent of GRU)
        float2 g2 = *reinterpret_cast<const float2*>(G + tn*64 + 2*i);
        float ex[10];
        {
            const float* xr = X + tn*10;
            #pragma unroll
            for (int c = 0; c < 5; ++c){
                float2 v = *reinterpret_cast<const float2*>(xr + 2*c);
                ex[2*c] = v.x; ex[2*c+1] = v.y;
            }
        }

        if (t > 0){
            // ---- GRU (fp64): h_t = gru([z_{t-1}, a_{t-1}], h_{t-1}) ----
            float ar[16];
            {
                const float4* arow = reinterpret_cast<const float4*>(A + ((size_t)(t-1)*NB + n)*16);
                #pragma unroll
                for (int c = 0; c < 4; ++c){
                    float4 v = arow[c];
                    ar[4*c+0]=v.x; ar[4*c+1]=v.y; ar[4*c+2]=v.z; ar[4*c+3]=v.w;
                }
            }
            double gr = br, gz = bz, gn = bni, hn = bnh;
            #pragma unroll
            for (int g = 0; g < 8; ++g){   // one-hot z part: gather selected columns
                int col = zsel[g];
                gr += (double)sWihz[i][col];
                gz += (double)sWihz[32+i][col];
                gn += (double)sWihz[64+i][col];
            }
            #pragma unroll
            for (int k = 0; k < 16; ++k){  // dense a part
                double ak = (double)ar[k];
                gr = fma((double)sWiha[i][k],    ak, gr);
                gz = fma((double)sWiha[32+i][k], ak, gz);
                gn = fma((double)sWiha[64+i][k], ak, gn);
            }
            #pragma unroll
            for (int k = 0; k < 32; ++k){  // hidden part
                gr = fma((double)whh[0][k], h[k], gr);
                gz = fma((double)whh[1][k], h[k], gz);
                hn = fma((double)whh[2][k], h[k], hn);
            }
            double r   = 1.0 / (1.0 + exp(-gr));
            double zg  = 1.0 / (1.0 + exp(-gz));
            double arg = gn + r * hn;
            double e2  = exp(2.0 * arg);
            double nn  = 1.0 - 2.0 / (e2 + 1.0);
            hown = (1.0 - zg) * nn + zg * hown;

            // broadcast h_new across the element's 32 lanes (same wave -> no barrier)
            sH[e][i] = hown;
            #pragma unroll
            for (int c = 0; c < 16; ++c){
                double2 v = *reinterpret_cast<const double2*>(&sH[e][2*c]);
                h[2*c] = v.x; h[2*c+1] = v.y;
            }
        }

        // h_all output (fp32)
        out[HOFF + tn*32 + i] = (float)hown;

        // ---- ENC (fp64 logits): argmax(logits + gumbel), lowest index on tie ----
        double l0 = be0, l1 = be1;
        #pragma unroll
        for (int k = 0; k < 32; ++k){
            float2 w = *reinterpret_cast<const float2*>(&sWenchT[k][2*i]);
            l0 = fma((double)w.x, h[k], l0);
            l1 = fma((double)w.y, h[k], l1);
        }
        #pragma unroll
        for (int k = 0; k < 10; ++k){
            float2 w = *reinterpret_cast<const float2*>(&sWenceT[k][2*i]);
            double ek = (double)ex[k];
            l0 = fma((double)w.x, ek, l0);
            l1 = fma((double)w.y, ek, l1);
        }
        double y0 = l0 + (double)g2.x, y1 = l1 + (double)g2.y;
        double m; int idxv;
        if (y1 > y0){ m = y1; idxv = 2*i + 1; } else { m = y0; idxv = 2*i; }
        #pragma unroll
        for (int d = 1; d <= 2; d <<= 1){   // butterfly argmax over the 4-lane cluster
            double mo = __shfl_xor(m, d, 64);
            int    io = __shfl_xor(idxv, d, 64);
            if (mo > m || (mo == m && io < idxv)){ m = mo; idxv = io; }
        }

        // z one-hot output (fp32): reference's one_hot + probs - probs -> {0, 1(+1e-7)}
        {
            float2 zv;
            zv.x = (idxv == 2*i    ) ? 1.0f : 0.0f;
            zv.y = (idxv == 2*i + 1) ? 1.0f : 0.0f;
            *reinterpret_cast<float2*>(out + ZOFF + tn*64 + 2*i) = zv;
        }

        // distribute the 8 group winners to every lane of the element
        #pragma unroll
        for (int g = 0; g < 8; ++g){
            zsel[g] = __shfl(idxv, base + 4*g, 64);
        }

        // ---- DEC (fp64 accum, fp32 out): lanes 0..9 ----
        if (i < 10){
            double acc = (double)bd;
            #pragma unroll
            for (int c = 0; c < 8; ++c){
                float4 w = *reinterpret_cast<const float4*>(&sWdech[i][4*c]);
                acc = fma((double)w.x, h[4*c+0], acc);
                acc = fma((double)w.y, h[4*c+1], acc);
                acc = fma((double)w.z, h[4*c+2], acc);
                acc = fma((double)w.w, h[4*c+3], acc);
            }
            #pragma unroll
            for (int g = 0; g < 8; ++g) acc += (double)sWdecz[i][zsel[g]];
            out[tn*10 + i] = (float)acc;
        }
    }
}

extern "C" void kernel_launch(void* const* d_in, const int* in_sizes, int n_in,
                              void* d_out, int out_size, void* d_ws, size_t ws_size,
                              hipStream_t stream)
{
    // Defensive input binding by unique element count (no-op if dict order holds).
    const float *x   = (const float*)d_in[0];
    const float *a   = (const float*)d_in[1];
    const float *h0  = (const float*)d_in[2];
    const float *g   = (const float*)d_in[3];
    const float *wih = (const float*)d_in[4];
    const float *bih = (const float*)d_in[5];
    const float *whh = (const float*)d_in[6];
    const float *bhh = (const float*)d_in[7];
    const float *wenc= (const float*)d_in[8];
    const float *benc= (const float*)d_in[9];
    const float *wdec= (const float*)d_in[10];
    const float *bdec= (const float*)d_in[11];

    if (n_in == 12) {
        const float *b96a = nullptr, *b96b = nullptr;
        const float *tx=nullptr,*ta=nullptr,*th0=nullptr,*tg=nullptr,*twih=nullptr,
                    *twhh=nullptr,*twenc=nullptr,*tbenc=nullptr,*twdec=nullptr,*tbdec=nullptr;
        for (int k = 0; k < 12; ++k) {
            const float* p = (const float*)d_in[k];
            switch (in_sizes[k]) {
                case 10485760: tx = p;    break;  // x   (256*4096*10)
                case 16777216: ta = p;    break;  // a   (256*4096*16)
                case 131072:   th0 = p;   break;  // h0  (4096*32)
                case 67108864: tg = p;    break;  // gumbel (256*4096*64)
                case 7680:     twih = p;  break;  // W_ih (96*80)
                case 3072:     twhh = p;  break;  // W_hh (96*32)
                case 2688:     twenc = p; break;  // W_enc (64*42)
                case 64:       tbenc = p; break;  // b_enc
                case 960:      twdec = p; break;  // W_dec (10*96)
                case 10:       tbdec = p; break;  // b_dec
                case 96:       if (!b96a) b96a = p; else b96b = p; break; // b_ih / b_hh (both zero)
                default: break;
            }
        }
        if (tx && ta && th0 && tg && twih && twhh && twenc && tbenc && twdec && tbdec && b96a && b96b) {
            x = tx; a = ta; h0 = th0; g = tg;
            wih = twih; whh = twhh; wenc = twenc; benc = tbenc; wdec = twdec; bdec = tbdec;
            bih = b96a; bhh = b96b;
        }
    }

    rssm_kernel<<<512, 256, 0, stream>>>(
        x, a, h0, g, wih, bih, whh, bhh, wenc, benc, wdec, bdec,
        (float*)d_out);
}